// Round 5
// baseline (185.597 us; speedup 1.0000x reference)
//
#include <hip/hip_runtime.h>

#define D 640
#define HID 64
#define NITER 64
#define ROWS 4           // rows per block == waves per block
#define BLOCK 256

typedef float v2f __attribute__((ext_vector_type(2)));

// ---- DPP wave64 reductions (VALU pipe only) ----
#define DPP_ADD_STEP(v, ctrl, rmask)                                          \
    v += __builtin_bit_cast(float, __builtin_amdgcn_update_dpp(               \
             0, __builtin_bit_cast(int, v), ctrl, rmask, 0xf, true))
#define DPP_MAX_STEP(v, ctrl, rmask)                                          \
    v = fmaxf(v, __builtin_bit_cast(float, __builtin_amdgcn_update_dpp(       \
             __builtin_bit_cast(int, v), __builtin_bit_cast(int, v),          \
             ctrl, rmask, 0xf, false)))

__device__ __forceinline__ float wave_sum_dpp(float v) {
    DPP_ADD_STEP(v, 0x111, 0xf);  // row_shr:1
    DPP_ADD_STEP(v, 0x112, 0xf);  // row_shr:2
    DPP_ADD_STEP(v, 0x114, 0xf);  // row_shr:4
    DPP_ADD_STEP(v, 0x118, 0xf);  // row_shr:8
    DPP_ADD_STEP(v, 0x142, 0xa);  // row_bcast:15
    DPP_ADD_STEP(v, 0x143, 0xc);  // row_bcast:31
    return __builtin_bit_cast(float,
        __builtin_amdgcn_readlane(__builtin_bit_cast(int, v), 63));
}
__device__ __forceinline__ float wave_max_dpp(float v) {
    DPP_MAX_STEP(v, 0x111, 0xf);
    DPP_MAX_STEP(v, 0x112, 0xf);
    DPP_MAX_STEP(v, 0x114, 0xf);
    DPP_MAX_STEP(v, 0x118, 0xf);
    DPP_MAX_STEP(v, 0x142, 0xa);
    DPP_MAX_STEP(v, 0x143, 0xc);
    return __builtin_bit_cast(float,
        __builtin_amdgcn_readlane(__builtin_bit_cast(int, v), 63));
}

__global__ __launch_bounds__(BLOCK) void dimmask_kernel(
    const float* __restrict__ x, const float* __restrict__ W1,
    const float* __restrict__ b1, const float* __restrict__ W2,
    const float* __restrict__ b2, float* __restrict__ out)
{
    constexpr float INV_T = 1.0f / 0.07f;
    constexpr float LOG2E = 1.4426950408889634f;
    constexpr float TEMP  = 0.07f;

    __shared__ float lds_a[ROWS][D];          // x rows, then ht
    __shared__ float lds_part[4][ROWS][HID];
    __shared__ float lds_hid[ROWS][HID];

    const int tid  = threadIdx.x;
    const int row0 = blockIdx.x * ROWS;

    // ---- stage x rows into LDS (coalesced float4) ----
    {
        const float4* xv  = (const float4*)(x + (size_t)row0 * D);
        float4*       lxv = (float4*)(&lds_a[0][0]);
        for (int i = tid; i < ROWS * D / 4; i += BLOCK) lxv[i] = xv[i];
    }
    __syncthreads();

    // ---- GEMM1: hid[r][k] = relu(sum_t x[r][t]*W1[t][k] + b1[k]) ----
    {
        const int k = tid & 63, c = tid >> 6;
        float acc[ROWS] = {0.f, 0.f, 0.f, 0.f};
        const int q0 = c * 40;
#pragma unroll 4
        for (int q = q0; q < q0 + 40; ++q) {
            const int tb = q * 4;
            float w0 = W1[(tb + 0) * HID + k];
            float w1 = W1[(tb + 1) * HID + k];
            float w2 = W1[(tb + 2) * HID + k];
            float w3 = W1[(tb + 3) * HID + k];
#pragma unroll
            for (int r = 0; r < ROWS; ++r) {
                float4 xa = ((const float4*)&lds_a[r][0])[q];
                acc[r] += xa.x * w0 + xa.y * w1 + xa.z * w2 + xa.w * w3;
            }
        }
#pragma unroll
        for (int r = 0; r < ROWS; ++r) lds_part[c][r][k] = acc[r];
    }
    __syncthreads();
    {
        const int r = tid >> 6, k = tid & 63;
        float s = lds_part[0][r][k] + lds_part[1][r][k]
                + lds_part[2][r][k] + lds_part[3][r][k] + b1[k];
        lds_hid[r][k] = fmaxf(s, 0.f);
    }
    __syncthreads();

    // ---- GEMM2: ht[r][j] = -h*log2e/T over dead x in lds_a ----
    for (int j = tid; j < D; j += BLOCK) {
        float acc[ROWS] = {0.f, 0.f, 0.f, 0.f};
#pragma unroll 4
        for (int k4 = 0; k4 < HID / 4; ++k4) {
            const int kb = k4 * 4;
            float w0 = W2[(kb + 0) * D + j];
            float w1 = W2[(kb + 1) * D + j];
            float w2 = W2[(kb + 2) * D + j];
            float w3 = W2[(kb + 3) * D + j];
#pragma unroll
            for (int r = 0; r < ROWS; ++r) {
                float4 hh = ((const float4*)&lds_hid[r][0])[k4];
                acc[r] += hh.x * w0 + hh.y * w1 + hh.z * w2 + hh.w * w3;
            }
        }
        float bb = b2[j];
#pragma unroll
        for (int r = 0; r < ROWS; ++r)
            lds_a[r][j] = -(acc[r] + bb) * (LOG2E * INV_T);
    }
    __syncthreads();

    // ---- Phase B: one wave per row; packed f32, branchless, ROLLED loop ----
    const int r = tid >> 6, l = tid & 63;
    v2f E2[5], e2[5];
    {
        float ht[10], hmax = -3.0e38f;
#pragma unroll
        for (int u = 0; u < 10; ++u) {
            ht[u] = lds_a[r][l + 64 * u];
            hmax = fmaxf(hmax, ht[u]);
        }
        hmax = wave_max_dpp(hmax);
#pragma unroll
        for (int u = 0; u < 5; ++u) {
            E2[u].x = __builtin_amdgcn_exp2f(fmaxf(ht[2 * u]     - hmax, -80.f));
            E2[u].y = __builtin_amdgcn_exp2f(fmaxf(ht[2 * u + 1] - hmax, -80.f));
            e2[u] = E2[u];   // w = 1
        }
    }

    const v2f K1  = {1.0f, 1.0f};
    const v2f P2v = {-0.1020408f, -0.1020408f};   // (1-y)^(2/7) deg-2 Taylor
    const v2f P1v = {-0.2857143f, -0.2857143f};

    // Small rolled body (~60 instrs) -- must NOT be unrolled: keeps the hot
    // loop resident in I$ for all 8 waves/SIMD (full unroll = 64x body streams
    // ~25KB of code per pass -> I-fetch bound; suspected R2-R4 overhead).
#pragma unroll 1
    for (int it = 0; it < NITER; ++it) {
        v2f t01 = e2[0] + e2[1], t23 = e2[2] + e2[3];
        v2f s2 = (t01 + t23) + e2[4];
        float s = s2.x + s2.y;
        s = wave_sum_dpp(s);
        float rs = __builtin_amdgcn_rcpf(s);
#pragma unroll
        for (int u = 0; u < 5; ++u) {
            v2f y  = e2[u] * rs;
            v2f f  = K1 - y;
            v2f f2 = f * f;
            v2f f4 = f2 * f2;
            v2f f8 = f4 * f4;
            v2f f14 = f8 * f4 * f2;                    // even powers: >= 0
            v2f p = __builtin_elementwise_fma(P2v, y, P1v);
            p = __builtin_elementwise_fma(p, y, K1);   // (1-y)^(2/7) approx
            e2[u] *= f14 * p;                          // (1-y)^(100/7)
        }
    }

    // ---- epilogue: w = e/E, m = w^T, out = m*x ----
    const float* xrow = x + (size_t)(row0 + r) * D;
    float* orow = out + (size_t)(row0 + r) * D;
#pragma unroll
    for (int u = 0; u < 5; ++u) {
        float w0 = e2[u].x * __builtin_amdgcn_rcpf(E2[u].x);
        float w1 = e2[u].y * __builtin_amdgcn_rcpf(E2[u].y);
        float m0 = __builtin_amdgcn_exp2f(TEMP * __builtin_amdgcn_logf(w0));
        float m1 = __builtin_amdgcn_exp2f(TEMP * __builtin_amdgcn_logf(w1));
        int j0 = l + 128 * u, j1 = j0 + 64;
        orow[j0] = m0 * xrow[j0];
        orow[j1] = m1 * xrow[j1];
    }
}

extern "C" void kernel_launch(void* const* d_in, const int* in_sizes, int n_in,
                              void* d_out, int out_size, void* d_ws, size_t ws_size,
                              hipStream_t stream) {
    const float* x  = (const float*)d_in[0];
    const float* W1 = (const float*)d_in[1];
    const float* b1 = (const float*)d_in[2];
    const float* W2 = (const float*)d_in[3];
    const float* b2 = (const float*)d_in[4];
    float* out = (float*)d_out;

    const int B = in_sizes[0] / D;            // 8192
    dim3 grid(B / ROWS), block(BLOCK);
    hipLaunchKernelGGL(dimmask_kernel, grid, block, 0, stream, x, W1, b1, W2, b2, out);
}